// Round 2
// baseline (2283.734 us; speedup 1.0000x reference)
//
#include <hip/hip_runtime.h>
#include <hip/hip_fp16.h>

typedef _Float16 half8 __attribute__((ext_vector_type(8)));
typedef _Float16 half4v __attribute__((ext_vector_type(4)));
typedef float floatx4 __attribute__((ext_vector_type(4)));

constexpr int BATCH = 64, SEQ = 64, DM = 2048, NHEAD = 8, HDIM = 256, FF = 16384;

__device__ __forceinline__ float f16r(float x) { return (float)(_Float16)x; }

__device__ __forceinline__ void gld_lds16(const _Float16* g, _Float16* l) {
  __builtin_amdgcn_global_load_lds(
      (const __attribute__((address_space(1))) void*)g,
      (__attribute__((address_space(3))) void*)l, 16, 0, 0);
}

__device__ __forceinline__ float gelu_tanh(float x) {
  float z = 1.5957691216057308f * (x + 0.044715f * x * x * x);  // 2*0.79788456*(...)
  float t = __expf(z);                                          // tanh = (t-1)/(t+1)
  return 0.5f * x * (1.0f + (t - 1.0f) / (t + 1.0f));
}

// ---------------- f32 -> f16 convert (8 elems/thread) ----------------
__global__ __launch_bounds__(256) void convert_f16(
    const float* __restrict__ s, _Float16* __restrict__ d, int n8) {
  int t = blockIdx.x * 256 + threadIdx.x;
  if (t >= n8) return;
  const float4* sp = (const float4*)s + (size_t)t * 2;
  float4 x = sp[0], y = sp[1];
  half8 h;
  h[0] = (_Float16)x.x; h[1] = (_Float16)x.y; h[2] = (_Float16)x.z; h[3] = (_Float16)x.w;
  h[4] = (_Float16)y.x; h[5] = (_Float16)y.y; h[6] = (_Float16)y.z; h[7] = (_Float16)y.w;
  ((half8*)d)[t] = h;
}

// ---------------- RMSNorm: f32 in -> f16 out ----------------
__global__ __launch_bounds__(256) void rmsnorm_kernel(
    const float* __restrict__ x, const float* __restrict__ w, _Float16* __restrict__ out) {
  const int row = blockIdx.x;
  const float4* xr = (const float4*)(x + (size_t)row * DM);
  const int tid = threadIdx.x;
  float4 a = xr[tid];
  float4 b = xr[tid + 256];
  float s = a.x*a.x + a.y*a.y + a.z*a.z + a.w*a.w
          + b.x*b.x + b.y*b.y + b.z*b.z + b.w*b.w;
  #pragma unroll
  for (int off = 32; off > 0; off >>= 1) s += __shfl_xor(s, off, 64);
  __shared__ float ps[4];
  if ((tid & 63) == 0) ps[tid >> 6] = s;
  __syncthreads();
  const float rs = rsqrtf((ps[0] + ps[1] + ps[2] + ps[3]) * (1.0f / DM) + 1e-6f);
  const float4* wr = (const float4*)w;
  float4 w1 = wr[tid], w2 = wr[tid + 256];
  half4v o1, o2;
  o1[0] = (_Float16)(a.x * rs * (1.f + w1.x));
  o1[1] = (_Float16)(a.y * rs * (1.f + w1.y));
  o1[2] = (_Float16)(a.z * rs * (1.f + w1.z));
  o1[3] = (_Float16)(a.w * rs * (1.f + w1.w));
  o2[0] = (_Float16)(b.x * rs * (1.f + w2.x));
  o2[1] = (_Float16)(b.y * rs * (1.f + w2.y));
  o2[2] = (_Float16)(b.z * rs * (1.f + w2.z));
  o2[3] = (_Float16)(b.w * rs * (1.f + w2.w));
  half4v* op = (half4v*)(out + (size_t)row * DM);
  op[tid] = o1;
  op[tid + 256] = o2;
}

// ======================================================================
// m97-style GEMM: C[M,N] = A[M,K]f16 * B[N,K]f16^T (+Res), global_load_lds
// LDS tiles contiguous 128x32 f16 (NO padding: lds dst = base + lane*16).
// ======================================================================
template<int EPI>
__global__ __launch_bounds__(256) void gemm_lds(
    const _Float16* __restrict__ A, const _Float16* __restrict__ B,
    float* C, const float* __restrict__ Res, int N, int K) {
  __shared__ _Float16 As[128 * 32];
  __shared__ _Float16 Bs[128 * 32];
  const int tid = threadIdx.x;
  const int lane = tid & 63, wave = tid >> 6;
  const int m0 = blockIdx.x * 128, n0 = blockIdx.y * 128;
  const int wm = (wave >> 1) * 64, wn = (wave & 1) * 64;
  const int lr = lane & 15, lk = (lane >> 4) * 8;
  // staging: wave w, inst i covers LDS halfs [(w*2+i)*512, +512): rows (w*2+i)*16 + lane/4
  const int srow = wave * 32 + (lane >> 2);
  const int scol = (lane & 3) * 8;
  const _Float16* Ag0 = A + (size_t)(m0 + srow) * K + scol;
  const _Float16* Ag1 = Ag0 + (size_t)16 * K;
  const _Float16* Bg0 = B + (size_t)(n0 + srow) * K + scol;
  const _Float16* Bg1 = Bg0 + (size_t)16 * K;
  _Float16* lA0 = As + wave * 1024;
  _Float16* lA1 = As + wave * 1024 + 512;
  _Float16* lB0 = Bs + wave * 1024;
  _Float16* lB1 = Bs + wave * 1024 + 512;
  floatx4 acc[4][4];
  #pragma unroll
  for (int i = 0; i < 4; ++i)
    #pragma unroll
    for (int j = 0; j < 4; ++j) acc[i][j] = (floatx4){0.f, 0.f, 0.f, 0.f};

  for (int kt = 0; kt < K; kt += 32) {
    gld_lds16(Ag0 + kt, lA0);
    gld_lds16(Ag1 + kt, lA1);
    gld_lds16(Bg0 + kt, lB0);
    gld_lds16(Bg1 + kt, lB1);
    __syncthreads();
    half8 af[4], bf[4];
    #pragma unroll
    for (int i = 0; i < 4; ++i) af[i] = *(const half8*)&As[(wm + i * 16 + lr) * 32 + lk];
    #pragma unroll
    for (int j = 0; j < 4; ++j) bf[j] = *(const half8*)&Bs[(wn + j * 16 + lr) * 32 + lk];
    #pragma unroll
    for (int i = 0; i < 4; ++i)
      #pragma unroll
      for (int j = 0; j < 4; ++j)
        acc[i][j] = __builtin_amdgcn_mfma_f32_16x16x32_f16(af[i], bf[j], acc[i][j], 0, 0, 0);
    __syncthreads();
  }
  const int mb = m0 + wm + (lane >> 4) * 4;
  const int nb = n0 + wn + (lane & 15);
  #pragma unroll
  for (int i = 0; i < 4; ++i)
    #pragma unroll
    for (int j = 0; j < 4; ++j)
      #pragma unroll
      for (int r = 0; r < 4; ++r) {
        size_t idx = (size_t)(mb + i * 16 + r) * N + (nb + j * 16);
        float val = acc[i][j][r];
        if constexpr (EPI == 1) val += Res[idx];
        C[idx] = val;
      }
}

// fused gate+up with global_load_lds; act = gelu(gate)*up -> f16
__global__ __launch_bounds__(256) void gateup_lds(
    const _Float16* __restrict__ A, const _Float16* __restrict__ Wg,
    const _Float16* __restrict__ Wu, _Float16* __restrict__ Act) {
  const int K = DM;
  __shared__ _Float16 As[128 * 32];
  __shared__ _Float16 Gs[128 * 32];
  __shared__ _Float16 Us[128 * 32];
  const int tid = threadIdx.x;
  const int lane = tid & 63, wave = tid >> 6;
  const int m0 = blockIdx.x * 128, n0 = blockIdx.y * 128;
  const int wm = (wave >> 1) * 64, wn = (wave & 1) * 64;
  const int lr = lane & 15, lk = (lane >> 4) * 8;
  const int srow = wave * 32 + (lane >> 2);
  const int scol = (lane & 3) * 8;
  const _Float16* Ag0 = A + (size_t)(m0 + srow) * K + scol;
  const _Float16* Ag1 = Ag0 + (size_t)16 * K;
  const _Float16* Gg0 = Wg + (size_t)(n0 + srow) * K + scol;
  const _Float16* Gg1 = Gg0 + (size_t)16 * K;
  const _Float16* Ug0 = Wu + (size_t)(n0 + srow) * K + scol;
  const _Float16* Ug1 = Ug0 + (size_t)16 * K;
  _Float16* lA0 = As + wave * 1024; _Float16* lA1 = lA0 + 512;
  _Float16* lG0 = Gs + wave * 1024; _Float16* lG1 = lG0 + 512;
  _Float16* lU0 = Us + wave * 1024; _Float16* lU1 = lU0 + 512;
  floatx4 ag[4][4], au[4][4];
  #pragma unroll
  for (int i = 0; i < 4; ++i)
    #pragma unroll
    for (int j = 0; j < 4; ++j) {
      ag[i][j] = (floatx4){0.f, 0.f, 0.f, 0.f};
      au[i][j] = (floatx4){0.f, 0.f, 0.f, 0.f};
    }
  for (int kt = 0; kt < K; kt += 32) {
    gld_lds16(Ag0 + kt, lA0);
    gld_lds16(Ag1 + kt, lA1);
    gld_lds16(Gg0 + kt, lG0);
    gld_lds16(Gg1 + kt, lG1);
    gld_lds16(Ug0 + kt, lU0);
    gld_lds16(Ug1 + kt, lU1);
    __syncthreads();
    half8 af[4], bg[4], bu[4];
    #pragma unroll
    for (int i = 0; i < 4; ++i) af[i] = *(const half8*)&As[(wm + i * 16 + lr) * 32 + lk];
    #pragma unroll
    for (int j = 0; j < 4; ++j) {
      bg[j] = *(const half8*)&Gs[(wn + j * 16 + lr) * 32 + lk];
      bu[j] = *(const half8*)&Us[(wn + j * 16 + lr) * 32 + lk];
    }
    #pragma unroll
    for (int i = 0; i < 4; ++i)
      #pragma unroll
      for (int j = 0; j < 4; ++j) {
        ag[i][j] = __builtin_amdgcn_mfma_f32_16x16x32_f16(af[i], bg[j], ag[i][j], 0, 0, 0);
        au[i][j] = __builtin_amdgcn_mfma_f32_16x16x32_f16(af[i], bu[j], au[i][j], 0, 0, 0);
      }
    __syncthreads();
  }
  const int mb = m0 + wm + (lane >> 4) * 4;
  const int nb = n0 + wn + (lane & 15);
  #pragma unroll
  for (int i = 0; i < 4; ++i)
    #pragma unroll
    for (int j = 0; j < 4; ++j)
      #pragma unroll
      for (int r = 0; r < 4; ++r) {
        size_t idx = (size_t)(mb + i * 16 + r) * FF + (nb + j * 16);
        Act[idx] = (_Float16)(gelu_tanh(ag[i][j][r]) * au[i][j][r]);
      }
}

// ---------------- legacy (R1) GEMMs: f32 weights, in-loop convert ----------------
template<int EPI>
__global__ __launch_bounds__(256, 2) void gemm_f16(
    const _Float16* __restrict__ A, const float* __restrict__ Bw,
    float* C, const float* Res, int N, int K) {
  const int m0 = blockIdx.x * 128;
  const int n0 = blockIdx.y * 128;
  __shared__ _Float16 As[128 * 40];
  __shared__ _Float16 Bs[128 * 40];
  const int tid = threadIdx.x;
  const int lane = tid & 63;
  const int wave = tid >> 6;
  const int wm = (wave >> 1) * 64, wn = (wave & 1) * 64;
  const int lr = lane & 15, lk = (lane >> 4) * 8;
  const int r2 = tid >> 1, kh = (tid & 1) * 16;
  const _Float16* Ag = A + (size_t)(m0 + r2) * K + kh;
  const float* Bg = Bw + (size_t)(n0 + r2) * K + kh;
  _Float16* AsW = &As[r2 * 40 + kh];
  _Float16* BsW = &Bs[r2 * 40 + kh];
  floatx4 acc[4][4];
  #pragma unroll
  for (int i = 0; i < 4; ++i)
    #pragma unroll
    for (int j = 0; j < 4; ++j) acc[i][j] = (floatx4){0.f, 0.f, 0.f, 0.f};
  for (int kt = 0; kt < K; kt += 32) {
    float4 a0 = *(const float4*)(Ag);
    float4 a1 = *(const float4*)(Ag + 8);
    float4 b0 = *(const float4*)(Bg);
    float4 b1 = *(const float4*)(Bg + 4);
    float4 b2 = *(const float4*)(Bg + 8);
    float4 b3 = *(const float4*)(Bg + 12);
    Ag += 32; Bg += 32;
    half8 hb0, hb1;
    hb0[0]=(_Float16)b0.x; hb0[1]=(_Float16)b0.y; hb0[2]=(_Float16)b0.z; hb0[3]=(_Float16)b0.w;
    hb0[4]=(_Float16)b1.x; hb0[5]=(_Float16)b1.y; hb0[6]=(_Float16)b1.z; hb0[7]=(_Float16)b1.w;
    hb1[0]=(_Float16)b2.x; hb1[1]=(_Float16)b2.y; hb1[2]=(_Float16)b2.z; hb1[3]=(_Float16)b2.w;
    hb1[4]=(_Float16)b3.x; hb1[5]=(_Float16)b3.y; hb1[6]=(_Float16)b3.z; hb1[7]=(_Float16)b3.w;
    __syncthreads();
    *(float4*)AsW = a0;
    *(float4*)(AsW + 8) = a1;
    *(half8*)BsW = hb0;
    *(half8*)(BsW + 8) = hb1;
    __syncthreads();
    half8 af[4], bfr[4];
    #pragma unroll
    for (int i = 0; i < 4; ++i) af[i] = *(const half8*)&As[(wm + i * 16 + lr) * 40 + lk];
    #pragma unroll
    for (int j = 0; j < 4; ++j) bfr[j] = *(const half8*)&Bs[(wn + j * 16 + lr) * 40 + lk];
    #pragma unroll
    for (int i = 0; i < 4; ++i)
      #pragma unroll
      for (int j = 0; j < 4; ++j)
        acc[i][j] = __builtin_amdgcn_mfma_f32_16x16x32_f16(af[i], bfr[j], acc[i][j], 0, 0, 0);
  }
  const int mb = m0 + wm + (lane >> 4) * 4;
  const int nb = n0 + wn + (lane & 15);
  #pragma unroll
  for (int i = 0; i < 4; ++i)
    #pragma unroll
    for (int j = 0; j < 4; ++j)
      #pragma unroll
      for (int r = 0; r < 4; ++r) {
        size_t idx = (size_t)(mb + i * 16 + r) * N + (nb + j * 16);
        float val = acc[i][j][r];
        if constexpr (EPI == 1) val += Res[idx];
        C[idx] = val;
      }
}

__global__ __launch_bounds__(256, 2) void gemm_gateup(
    const _Float16* __restrict__ A, const float* __restrict__ Wg,
    const float* __restrict__ Wu, _Float16* __restrict__ Act) {
  const int K = DM;
  const int m0 = blockIdx.x * 128;
  const int n0 = blockIdx.y * 128;
  __shared__ _Float16 As[128 * 40];
  __shared__ _Float16 Bgs[128 * 40];
  __shared__ _Float16 Bus[128 * 40];
  const int tid = threadIdx.x;
  const int lane = tid & 63;
  const int wave = tid >> 6;
  const int wm = (wave >> 1) * 64, wn = (wave & 1) * 64;
  const int lr = lane & 15, lk = (lane >> 4) * 8;
  const int r2 = tid >> 1, kh = (tid & 1) * 16;
  const _Float16* Ag = A + (size_t)(m0 + r2) * K + kh;
  const float* Bgg = Wg + (size_t)(n0 + r2) * K + kh;
  const float* Bgu = Wu + (size_t)(n0 + r2) * K + kh;
  _Float16* AsW = &As[r2 * 40 + kh];
  _Float16* BgW = &Bgs[r2 * 40 + kh];
  _Float16* BuW = &Bus[r2 * 40 + kh];
  floatx4 ag[4][4], au[4][4];
  #pragma unroll
  for (int i = 0; i < 4; ++i)
    #pragma unroll
    for (int j = 0; j < 4; ++j) {
      ag[i][j] = (floatx4){0.f, 0.f, 0.f, 0.f};
      au[i][j] = (floatx4){0.f, 0.f, 0.f, 0.f};
    }
  for (int kt = 0; kt < K; kt += 32) {
    float4 a0 = *(const float4*)(Ag);
    float4 a1 = *(const float4*)(Ag + 8);
    float4 g0 = *(const float4*)(Bgg);
    float4 g1 = *(const float4*)(Bgg + 4);
    float4 g2 = *(const float4*)(Bgg + 8);
    float4 g3 = *(const float4*)(Bgg + 12);
    float4 u0 = *(const float4*)(Bgu);
    float4 u1 = *(const float4*)(Bgu + 4);
    float4 u2 = *(const float4*)(Bgu + 8);
    float4 u3 = *(const float4*)(Bgu + 12);
    Ag += 32; Bgg += 32; Bgu += 32;
    half8 hg0, hg1, hu0, hu1;
    hg0[0]=(_Float16)g0.x; hg0[1]=(_Float16)g0.y; hg0[2]=(_Float16)g0.z; hg0[3]=(_Float16)g0.w;
    hg0[4]=(_Float16)g1.x; hg0[5]=(_Float16)g1.y; hg0[6]=(_Float16)g1.z; hg0[7]=(_Float16)g1.w;
    hg1[0]=(_Float16)g2.x; hg1[1]=(_Float16)g2.y; hg1[2]=(_Float16)g2.z; hg1[3]=(_Float16)g2.w;
    hg1[4]=(_Float16)g3.x; hg1[5]=(_Float16)g3.y; hg1[6]=(_Float16)g3.z; hg1[7]=(_Float16)g3.w;
    hu0[0]=(_Float16)u0.x; hu0[1]=(_Float16)u0.y; hu0[2]=(_Float16)u0.z; hu0[3]=(_Float16)u0.w;
    hu0[4]=(_Float16)u1.x; hu0[5]=(_Float16)u1.y; hu0[6]=(_Float16)u1.z; hu0[7]=(_Float16)u1.w;
    hu1[0]=(_Float16)u2.x; hu1[1]=(_Float16)u2.y; hu1[2]=(_Float16)u2.z; hu1[3]=(_Float16)u2.w;
    hu1[4]=(_Float16)u3.x; hu1[5]=(_Float16)u3.y; hu1[6]=(_Float16)u3.z; hu1[7]=(_Float16)u3.w;
    __syncthreads();
    *(float4*)AsW = a0;
    *(float4*)(AsW + 8) = a1;
    *(half8*)BgW = hg0; *(half8*)(BgW + 8) = hg1;
    *(half8*)BuW = hu0; *(half8*)(BuW + 8) = hu1;
    __syncthreads();
    half8 af[4], bg[4], bu[4];
    #pragma unroll
    for (int i = 0; i < 4; ++i) af[i] = *(const half8*)&As[(wm + i * 16 + lr) * 40 + lk];
    #pragma unroll
    for (int j = 0; j < 4; ++j) {
      bg[j] = *(const half8*)&Bgs[(wn + j * 16 + lr) * 40 + lk];
      bu[j] = *(const half8*)&Bus[(wn + j * 16 + lr) * 40 + lk];
    }
    #pragma unroll
    for (int i = 0; i < 4; ++i)
      #pragma unroll
      for (int j = 0; j < 4; ++j) {
        ag[i][j] = __builtin_amdgcn_mfma_f32_16x16x32_f16(af[i], bg[j], ag[i][j], 0, 0, 0);
        au[i][j] = __builtin_amdgcn_mfma_f32_16x16x32_f16(af[i], bu[j], au[i][j], 0, 0, 0);
      }
  }
  const int mb = m0 + wm + (lane >> 4) * 4;
  const int nb = n0 + wn + (lane & 15);
  #pragma unroll
  for (int i = 0; i < 4; ++i)
    #pragma unroll
    for (int j = 0; j < 4; ++j)
      #pragma unroll
      for (int r = 0; r < 4; ++r) {
        size_t idx = (size_t)(mb + i * 16 + r) * FF + (nb + j * 16);
        Act[idx] = (_Float16)(gelu_tanh(ag[i][j][r]) * au[i][j][r]);
      }
}

// ---------------- RoPE (repo transpose bug: angle uses pos_ids[s,b]) ----------------
__global__ __launch_bounds__(256) void rope_kernel(
    float* __restrict__ x, const int* __restrict__ pos_ids,
    const float* __restrict__ inv_freq, int nh, int ld, int total) {
  int tid = blockIdx.x * 256 + threadIdx.x;
  if (tid >= total) return;
  int i = tid & 127;
  int rest = tid >> 7;
  int hh = rest % nh;
  int m = rest / nh;                 // b*64 + s
  int b = m >> 6, s = m & 63;
  int pos = pos_ids[s * 64 + b];     // transposed indexing (B==S)
  float fr = inv_freq[i] * (float)pos;
  float c = cosf(fr), sn = sinf(fr);
  size_t base = (size_t)m * ld + (size_t)hh * 256 + i;
  float x1 = x[base], x2 = x[base + 128];
  x[base] = x1 * c - x2 * sn;
  x[base + 128] = x2 * c + x1 * sn;
}

// ---------------- attention (strided q/k/v) ----------------
__global__ __launch_bounds__(256) void attn_kernel(
    const float* __restrict__ qbase, int qld,
    const float* __restrict__ kbase, int kld,
    const float* __restrict__ vbase, int vld,
    const float* __restrict__ mask, float* __restrict__ attn_out, _Float16* __restrict__ ctx) {
  const int bh = blockIdx.x;
  const int b = bh >> 3, h = bh & 7;
  __shared__ __align__(16) char smem[65536];
  const int tid = threadIdx.x;
  for (int it = 0; it < 16; ++it) {
    int f = it * 256 + tid;
    int t = f >> 6, d4 = f & 63;
    float4 kv = *(const float4*)(kbase + (size_t)(b * 64 + t) * kld + d4 * 4);
    int col = d4 ^ ((t >> 2) & 7);
    *(float4*)(smem + t * 1024 + col * 16) = kv;
  }
  __syncthreads();
  const int sg = tid >> 4, tg = tid & 15;
  const int s0 = sg * 4, t0 = tg * 4;
  float sc[4][4] = {};
  const float* qb = qbase + (size_t)(b * 64 + s0) * qld + h * HDIM;
  for (int d4 = 0; d4 < 64; ++d4) {
    float4 kvv[4];
    int col = d4 ^ (tg & 7);
    #pragma unroll
    for (int j = 0; j < 4; ++j)
      kvv[j] = *(const float4*)(smem + (t0 + j) * 1024 + col * 16);
    #pragma unroll
    for (int i = 0; i < 4; ++i) {
      float4 qv = *(const float4*)(qb + (size_t)i * qld + d4 * 4);
      #pragma unroll
      for (int j = 0; j < 4; ++j)
        sc[i][j] += qv.x * kvv[j].x + qv.y * kvv[j].y + qv.z * kvv[j].z + qv.w * kvv[j].w;
    }
  }
  float a16[4][4];
  const float* mrow = mask + (size_t)b * SEQ * SEQ;
  #pragma unroll
  for (int i = 0; i < 4; ++i) {
    const float4 mk = *(const float4*)(mrow + (size_t)(s0 + i) * SEQ + t0);
    float xh[4];
    xh[0] = f16r(sc[i][0] * 0.0625f + mk.x);
    xh[1] = f16r(sc[i][1] * 0.0625f + mk.y);
    xh[2] = f16r(sc[i][2] * 0.0625f + mk.z);
    xh[3] = f16r(sc[i][3] * 0.0625f + mk.w);
    float mx = fmaxf(fmaxf(xh[0], xh[1]), fmaxf(xh[2], xh[3]));
    #pragma unroll
    for (int off = 1; off < 16; off <<= 1) mx = fmaxf(mx, __shfl_xor(mx, off, 64));
    float ssum = 0.f;
    #pragma unroll
    for (int j = 0; j < 4; ++j) {
      float e = f16r(expf(f16r(xh[j] - mx)));
      a16[i][j] = e;
      ssum += e;
    }
    #pragma unroll
    for (int off = 1; off < 16; off <<= 1) ssum += __shfl_xor(ssum, off, 64);
    #pragma unroll
    for (int j = 0; j < 4; ++j) a16[i][j] = f16r(a16[i][j] / ssum);
  }
  float* ab = attn_out + (size_t)bh * SEQ * SEQ;
  #pragma unroll
  for (int i = 0; i < 4; ++i) {
    float4 av = {a16[i][0], a16[i][1], a16[i][2], a16[i][3]};
    *(float4*)(ab + (size_t)(s0 + i) * SEQ + t0) = av;
  }
  __syncthreads();
  float* as = (float*)smem;
  _Float16* vs = (_Float16*)(smem + 64 * 65 * 4);
  #pragma unroll
  for (int i = 0; i < 4; ++i)
    #pragma unroll
    for (int j = 0; j < 4; ++j)
      as[(s0 + i) * 65 + t0 + j] = a16[i][j];
  for (int it = 0; it < 16; ++it) {
    int f = it * 256 + tid;
    int t = f >> 6, d4 = f & 63;
    float4 vv = *(const float4*)(vbase + (size_t)(b * 64 + t) * vld + d4 * 4);
    half4v hv;
    hv[0] = (_Float16)vv.x; hv[1] = (_Float16)vv.y;
    hv[2] = (_Float16)vv.z; hv[3] = (_Float16)vv.w;
    *(half4v*)(vs + t * 264 + d4 * 4) = hv;
  }
  __syncthreads();
  floatx4 outv[4][4];
  #pragma unroll
  for (int i = 0; i < 4; ++i)
    #pragma unroll
    for (int u = 0; u < 4; ++u) outv[i][u] = (floatx4){0.f, 0.f, 0.f, 0.f};
  for (int t = 0; t < 64; ++t) {
    float av[4];
    #pragma unroll
    for (int i = 0; i < 4; ++i) av[i] = as[(s0 + i) * 65 + t];
    #pragma unroll
    for (int u = 0; u < 4; ++u) {
      half4v vh = *(const half4v*)(vs + t * 264 + tg * 4 + u * 64);
      floatx4 vf = {(float)vh[0], (float)vh[1], (float)vh[2], (float)vh[3]};
      #pragma unroll
      for (int i = 0; i < 4; ++i) outv[i][u] += vf * av[i];
    }
  }
  #pragma unroll
  for (int i = 0; i < 4; ++i)
    #pragma unroll
    for (int u = 0; u < 4; ++u) {
      half4v hv;
      hv[0] = (_Float16)outv[i][u][0];
      hv[1] = (_Float16)outv[i][u][1];
      hv[2] = (_Float16)outv[i][u][2];
      hv[3] = (_Float16)outv[i][u][3];
      *(half4v*)(ctx + (size_t)(b * 64 + s0 + i) * DM + h * HDIM + u * 64 + tg * 4) = hv;
    }
}

extern "C" void kernel_launch(void* const* d_in, const int* in_sizes, int n_in,
                              void* d_out, int out_size, void* d_ws, size_t ws_size,
                              hipStream_t stream) {
  const float* hs   = (const float*)d_in[0];
  const float* mask = (const float*)d_in[1];
  const int*   pos  = (const int*)d_in[2];
  const float* invf = (const float*)d_in[3];
  const float* wq   = (const float*)d_in[4];
  const float* wk   = (const float*)d_in[5];
  const float* wv   = (const float*)d_in[6];
  const float* wo   = (const float*)d_in[7];
  const float* wg   = (const float*)d_in[8];
  const float* wu   = (const float*)d_in[9];
  const float* wd   = (const float*)d_in[10];
  const float* ln1  = (const float*)d_in[11];
  const float* ln2  = (const float*)d_in[12];

  float* out_hidden = (float*)d_out;                 // (64,64,2048) f32
  float* out_attn   = out_hidden + 8388608;          // (64,8,64,64) f32

  const size_t FULL_NEED = 352321536;                // 336 MiB
  char* ws = (char*)d_ws;

  if (ws_size >= FULL_NEED) {
    // ---- full path: f16 weights + global_load_lds GEMMs ----
    _Float16* h_half = (_Float16*)(ws);                        // 16.8 MB
    _Float16* wg_h   = (_Float16*)(ws + 16777216);             // 67.1 MB
    _Float16* wu_h   = (_Float16*)(ws + 83886080);             // 67.1 MB
    _Float16* wd_h   = (_Float16*)(ws + 150994944);            // 67.1 MB
    char*     rx     = ws + 218103808;                         // union region (134.2 MB)
    _Float16* qkvw   = (_Float16*)(rx);                        // [2560][2048] f16
    _Float16* wo_h   = (_Float16*)(rx + 10485760);
    float*    qkv    = (float*)(rx + 18874368);                // [4096][2560] f32
    _Float16* ctx    = (_Float16*)(rx + 60817408);             // [4096][2048] f16
    _Float16* act    = (_Float16*)(rx);                        // [4096][16384] f16 (after attn/o-proj)

    convert_f16<<<2048, 256, 0, stream>>>(wq, qkvw, 524288);
    convert_f16<<<256,  256, 0, stream>>>(wk, qkvw + (size_t)2048 * 2048, 65536);
    convert_f16<<<256,  256, 0, stream>>>(wv, qkvw + (size_t)2304 * 2048, 65536);
    convert_f16<<<2048, 256, 0, stream>>>(wo, wo_h, 524288);
    convert_f16<<<16384, 256, 0, stream>>>(wg, wg_h, 4194304);
    convert_f16<<<16384, 256, 0, stream>>>(wu, wu_h, 4194304);
    convert_f16<<<16384, 256, 0, stream>>>(wd, wd_h, 4194304);

    rmsnorm_kernel<<<4096, 256, 0, stream>>>(hs, ln1, h_half);
    gemm_lds<0><<<dim3(32, 20), 256, 0, stream>>>(h_half, qkvw, qkv, nullptr, 2560, 2048);
    rope_kernel<<<18432, 256, 0, stream>>>(qkv, pos, invf, 9, 2560, 4096 * 9 * 128);
    attn_kernel<<<512, 256, 0, stream>>>(qkv, 2560, qkv + 2048, 2560, qkv + 2304, 2560,
                                         mask, out_attn, ctx);
    gemm_lds<1><<<dim3(32, 16), 256, 0, stream>>>(ctx, wo_h, out_hidden, hs, 2048, 2048);
    rmsnorm_kernel<<<4096, 256, 0, stream>>>(out_hidden, ln2, h_half);
    gateup_lds<<<dim3(32, 128), 256, 0, stream>>>(h_half, wg_h, wu_h, act);
    gemm_lds<1><<<dim3(32, 16), 256, 0, stream>>>(act, wd_h, out_hidden, out_hidden, 2048, 16384);
  } else {
    // ---- fallback: R1 structure (151 MB) ----
    _Float16* h_half = (_Float16*)ws;
    char* Creg = ws + (size_t)16777216;
    float*     qb  = (float*)(Creg);
    float*     kb  = (float*)(Creg + 33554432);
    float*     vb  = (float*)(Creg + 37748736);
    _Float16*  ctx = (_Float16*)(Creg + 41943040);
    _Float16*  act = (_Float16*)(Creg);

    rmsnorm_kernel<<<4096, 256, 0, stream>>>(hs, ln1, h_half);
    gemm_f16<0><<<dim3(32, 16), 256, 0, stream>>>(h_half, wq, qb, nullptr, 2048, 2048);
    gemm_f16<0><<<dim3(32, 2),  256, 0, stream>>>(h_half, wk, kb, nullptr, 256, 2048);
    gemm_f16<0><<<dim3(32, 2),  256, 0, stream>>>(h_half, wv, vb, nullptr, 256, 2048);
    rope_kernel<<<16384, 256, 0, stream>>>(qb, pos, invf, 8, 2048, 4096 * 8 * 128);
    rope_kernel<<<2048,  256, 0, stream>>>(kb, pos, invf, 1, 256, 4096 * 1 * 128);
    attn_kernel<<<512, 256, 0, stream>>>(qb, 2048, kb, 256, vb, 256, mask, out_attn, ctx);
    gemm_f16<1><<<dim3(32, 16), 256, 0, stream>>>(ctx, wo, out_hidden, hs, 2048, 2048);
    rmsnorm_kernel<<<4096, 256, 0, stream>>>(out_hidden, ln2, h_half);
    gemm_gateup<<<dim3(32, 128), 256, 0, stream>>>(h_half, wg, wu, act);
    gemm_f16<1><<<dim3(32, 16), 256, 0, stream>>>(act, wd, out_hidden, out_hidden, 2048, 16384);
  }
}

// Round 3
// 1808.135 us; speedup vs baseline: 1.2630x; 1.2630x over previous
//
#include <hip/hip_runtime.h>
#include <hip/hip_fp16.h>

typedef _Float16 half8 __attribute__((ext_vector_type(8)));
typedef _Float16 half4v __attribute__((ext_vector_type(4)));
typedef float floatx4 __attribute__((ext_vector_type(4)));

constexpr int BATCH = 64, SEQ = 64, DM = 2048, NHEAD = 8, HDIM = 256, FF = 16384;

__device__ __forceinline__ float f16r(float x) { return (float)(_Float16)x; }

__device__ __forceinline__ void gld_lds16(const _Float16* g, _Float16* l) {
  __builtin_amdgcn_global_load_lds(
      (const __attribute__((address_space(1))) void*)g,
      (__attribute__((address_space(3))) void*)l, 16, 0, 0);
}

__device__ __forceinline__ float gelu_tanh(float x) {
  float z = 1.5957691216057308f * (x + 0.044715f * x * x * x);  // 2*0.79788456*(...)
  float t = __expf(z);                                          // tanh = (t-1)/(t+1)
  return 0.5f * x * (1.0f + (t - 1.0f) / (t + 1.0f));
}

// ---------------- f32 -> f16 convert (8 elems/thread) ----------------
__global__ __launch_bounds__(256) void convert_f16(
    const float* __restrict__ s, _Float16* __restrict__ d, int n8) {
  int t = blockIdx.x * 256 + threadIdx.x;
  if (t >= n8) return;
  const float4* sp = (const float4*)s + (size_t)t * 2;
  float4 x = sp[0], y = sp[1];
  half8 h;
  h[0] = (_Float16)x.x; h[1] = (_Float16)x.y; h[2] = (_Float16)x.z; h[3] = (_Float16)x.w;
  h[4] = (_Float16)y.x; h[5] = (_Float16)y.y; h[6] = (_Float16)y.z; h[7] = (_Float16)y.w;
  ((half8*)d)[t] = h;
}

// ---------------- RMSNorm: f32 in -> f16 out ----------------
__global__ __launch_bounds__(256) void rmsnorm_kernel(
    const float* __restrict__ x, const float* __restrict__ w, _Float16* __restrict__ out) {
  const int row = blockIdx.x;
  const float4* xr = (const float4*)(x + (size_t)row * DM);
  const int tid = threadIdx.x;
  float4 a = xr[tid];
  float4 b = xr[tid + 256];
  float s = a.x*a.x + a.y*a.y + a.z*a.z + a.w*a.w
          + b.x*b.x + b.y*b.y + b.z*b.z + b.w*b.w;
  #pragma unroll
  for (int off = 32; off > 0; off >>= 1) s += __shfl_xor(s, off, 64);
  __shared__ float ps[4];
  if ((tid & 63) == 0) ps[tid >> 6] = s;
  __syncthreads();
  const float rs = rsqrtf((ps[0] + ps[1] + ps[2] + ps[3]) * (1.0f / DM) + 1e-6f);
  const float4* wr = (const float4*)w;
  float4 w1 = wr[tid], w2 = wr[tid + 256];
  half4v o1, o2;
  o1[0] = (_Float16)(a.x * rs * (1.f + w1.x));
  o1[1] = (_Float16)(a.y * rs * (1.f + w1.y));
  o1[2] = (_Float16)(a.z * rs * (1.f + w1.z));
  o1[3] = (_Float16)(a.w * rs * (1.f + w1.w));
  o2[0] = (_Float16)(b.x * rs * (1.f + w2.x));
  o2[1] = (_Float16)(b.y * rs * (1.f + w2.y));
  o2[2] = (_Float16)(b.z * rs * (1.f + w2.z));
  o2[3] = (_Float16)(b.w * rs * (1.f + w2.w));
  half4v* op = (half4v*)(out + (size_t)row * DM);
  op[tid] = o1;
  op[tid + 256] = o2;
}

// ======================================================================
// m97-style GEMM: C[M,N] = A[M,K]f16 * B[N,K]f16^T (+Res), global_load_lds
// LDS tiles contiguous 128x32 f16 (NO padding: lds dst = base + lane*16).
// ======================================================================
template<int EPI>
__global__ __launch_bounds__(256) void gemm_lds(
    const _Float16* __restrict__ A, const _Float16* __restrict__ B,
    float* C, const float* __restrict__ Res, int N, int K) {
  __shared__ _Float16 As[128 * 32];
  __shared__ _Float16 Bs[128 * 32];
  const int tid = threadIdx.x;
  const int lane = tid & 63, wave = tid >> 6;
  const int m0 = blockIdx.x * 128, n0 = blockIdx.y * 128;
  const int wm = (wave >> 1) * 64, wn = (wave & 1) * 64;
  const int lr = lane & 15, lk = (lane >> 4) * 8;
  const int srow = wave * 32 + (lane >> 2);
  const int scol = (lane & 3) * 8;
  const _Float16* Ag0 = A + (size_t)(m0 + srow) * K + scol;
  const _Float16* Ag1 = Ag0 + (size_t)16 * K;
  const _Float16* Bg0 = B + (size_t)(n0 + srow) * K + scol;
  const _Float16* Bg1 = Bg0 + (size_t)16 * K;
  _Float16* lA0 = As + wave * 1024;
  _Float16* lA1 = As + wave * 1024 + 512;
  _Float16* lB0 = Bs + wave * 1024;
  _Float16* lB1 = Bs + wave * 1024 + 512;
  floatx4 acc[4][4];
  #pragma unroll
  for (int i = 0; i < 4; ++i)
    #pragma unroll
    for (int j = 0; j < 4; ++j) acc[i][j] = (floatx4){0.f, 0.f, 0.f, 0.f};

  for (int kt = 0; kt < K; kt += 32) {
    gld_lds16(Ag0 + kt, lA0);
    gld_lds16(Ag1 + kt, lA1);
    gld_lds16(Bg0 + kt, lB0);
    gld_lds16(Bg1 + kt, lB1);
    __syncthreads();
    half8 af[4], bf[4];
    #pragma unroll
    for (int i = 0; i < 4; ++i) af[i] = *(const half8*)&As[(wm + i * 16 + lr) * 32 + lk];
    #pragma unroll
    for (int j = 0; j < 4; ++j) bf[j] = *(const half8*)&Bs[(wn + j * 16 + lr) * 32 + lk];
    #pragma unroll
    for (int i = 0; i < 4; ++i)
      #pragma unroll
      for (int j = 0; j < 4; ++j)
        acc[i][j] = __builtin_amdgcn_mfma_f32_16x16x32_f16(af[i], bf[j], acc[i][j], 0, 0, 0);
    __syncthreads();
  }
  const int mb = m0 + wm + (lane >> 4) * 4;
  const int nb = n0 + wn + (lane & 15);
  #pragma unroll
  for (int i = 0; i < 4; ++i)
    #pragma unroll
    for (int j = 0; j < 4; ++j)
      #pragma unroll
      for (int r = 0; r < 4; ++r) {
        size_t idx = (size_t)(mb + i * 16 + r) * N + (nb + j * 16);
        float val = acc[i][j][r];
        if constexpr (EPI == 1) val += Res[idx];
        C[idx] = val;
      }
}

// fused gate+up, wave tile 64x32 (x2 outputs) -> 64 AGPR: keeps >=2 waves/SIMD.
// Block tile 128x64: As 8KB, Gs/Us 4KB each. 4 gld + 8 ds_read + 16 MFMA / K-step.
__global__ __launch_bounds__(256) void gateup_lds(
    const _Float16* __restrict__ A, const _Float16* __restrict__ Wg,
    const _Float16* __restrict__ Wu, _Float16* __restrict__ Act) {
  const int K = DM;
  __shared__ _Float16 As[128 * 32];
  __shared__ _Float16 Gs[64 * 32];
  __shared__ _Float16 Us[64 * 32];
  const int tid = threadIdx.x;
  const int lane = tid & 63, wave = tid >> 6;
  const int m0 = blockIdx.x * 128, n0 = blockIdx.y * 64;
  const int wm = (wave >> 1) * 64, wn = (wave & 1) * 32;
  const int lr = lane & 15, lk = (lane >> 4) * 8;
  const int srowA = wave * 32 + (lane >> 2);
  const int srowB = wave * 16 + (lane >> 2);
  const int scol = (lane & 3) * 8;
  const _Float16* Ag0 = A + (size_t)(m0 + srowA) * K + scol;
  const _Float16* Ag1 = Ag0 + (size_t)16 * K;
  const _Float16* Gg = Wg + (size_t)(n0 + srowB) * K + scol;
  const _Float16* Ug = Wu + (size_t)(n0 + srowB) * K + scol;
  _Float16* lA0 = As + wave * 1024;
  _Float16* lA1 = lA0 + 512;
  _Float16* lG = Gs + wave * 512;
  _Float16* lU = Us + wave * 512;
  floatx4 ag[4][2], au[4][2];
  #pragma unroll
  for (int i = 0; i < 4; ++i)
    #pragma unroll
    for (int j = 0; j < 2; ++j) {
      ag[i][j] = (floatx4){0.f, 0.f, 0.f, 0.f};
      au[i][j] = (floatx4){0.f, 0.f, 0.f, 0.f};
    }
  for (int kt = 0; kt < K; kt += 32) {
    gld_lds16(Ag0 + kt, lA0);
    gld_lds16(Ag1 + kt, lA1);
    gld_lds16(Gg + kt, lG);
    gld_lds16(Ug + kt, lU);
    __syncthreads();
    half8 af[4], bg[2], bu[2];
    #pragma unroll
    for (int i = 0; i < 4; ++i) af[i] = *(const half8*)&As[(wm + i * 16 + lr) * 32 + lk];
    #pragma unroll
    for (int j = 0; j < 2; ++j) {
      bg[j] = *(const half8*)&Gs[(wn + j * 16 + lr) * 32 + lk];
      bu[j] = *(const half8*)&Us[(wn + j * 16 + lr) * 32 + lk];
    }
    #pragma unroll
    for (int i = 0; i < 4; ++i)
      #pragma unroll
      for (int j = 0; j < 2; ++j) {
        ag[i][j] = __builtin_amdgcn_mfma_f32_16x16x32_f16(af[i], bg[j], ag[i][j], 0, 0, 0);
        au[i][j] = __builtin_amdgcn_mfma_f32_16x16x32_f16(af[i], bu[j], au[i][j], 0, 0, 0);
      }
    __syncthreads();
  }
  const int mb = m0 + wm + (lane >> 4) * 4;
  const int nb = n0 + wn + (lane & 15);
  #pragma unroll
  for (int i = 0; i < 4; ++i)
    #pragma unroll
    for (int j = 0; j < 2; ++j)
      #pragma unroll
      for (int r = 0; r < 4; ++r) {
        size_t idx = (size_t)(mb + i * 16 + r) * FF + (nb + j * 16);
        Act[idx] = (_Float16)(gelu_tanh(ag[i][j][r]) * au[i][j][r]);
      }
}

// ---------------- legacy (R1) GEMMs: f32 weights, in-loop convert ----------------
template<int EPI>
__global__ __launch_bounds__(256, 2) void gemm_f16(
    const _Float16* __restrict__ A, const float* __restrict__ Bw,
    float* C, const float* Res, int N, int K) {
  const int m0 = blockIdx.x * 128;
  const int n0 = blockIdx.y * 128;
  __shared__ _Float16 As[128 * 40];
  __shared__ _Float16 Bs[128 * 40];
  const int tid = threadIdx.x;
  const int lane = tid & 63;
  const int wave = tid >> 6;
  const int wm = (wave >> 1) * 64, wn = (wave & 1) * 64;
  const int lr = lane & 15, lk = (lane >> 4) * 8;
  const int r2 = tid >> 1, kh = (tid & 1) * 16;
  const _Float16* Ag = A + (size_t)(m0 + r2) * K + kh;
  const float* Bg = Bw + (size_t)(n0 + r2) * K + kh;
  _Float16* AsW = &As[r2 * 40 + kh];
  _Float16* BsW = &Bs[r2 * 40 + kh];
  floatx4 acc[4][4];
  #pragma unroll
  for (int i = 0; i < 4; ++i)
    #pragma unroll
    for (int j = 0; j < 4; ++j) acc[i][j] = (floatx4){0.f, 0.f, 0.f, 0.f};
  for (int kt = 0; kt < K; kt += 32) {
    float4 a0 = *(const float4*)(Ag);
    float4 a1 = *(const float4*)(Ag + 8);
    float4 b0 = *(const float4*)(Bg);
    float4 b1 = *(const float4*)(Bg + 4);
    float4 b2 = *(const float4*)(Bg + 8);
    float4 b3 = *(const float4*)(Bg + 12);
    Ag += 32; Bg += 32;
    half8 hb0, hb1;
    hb0[0]=(_Float16)b0.x; hb0[1]=(_Float16)b0.y; hb0[2]=(_Float16)b0.z; hb0[3]=(_Float16)b0.w;
    hb0[4]=(_Float16)b1.x; hb0[5]=(_Float16)b1.y; hb0[6]=(_Float16)b1.z; hb0[7]=(_Float16)b1.w;
    hb1[0]=(_Float16)b2.x; hb1[1]=(_Float16)b2.y; hb1[2]=(_Float16)b2.z; hb1[3]=(_Float16)b2.w;
    hb1[4]=(_Float16)b3.x; hb1[5]=(_Float16)b3.y; hb1[6]=(_Float16)b3.z; hb1[7]=(_Float16)b3.w;
    __syncthreads();
    *(float4*)AsW = a0;
    *(float4*)(AsW + 8) = a1;
    *(half8*)BsW = hb0;
    *(half8*)(BsW + 8) = hb1;
    __syncthreads();
    half8 af[4], bfr[4];
    #pragma unroll
    for (int i = 0; i < 4; ++i) af[i] = *(const half8*)&As[(wm + i * 16 + lr) * 40 + lk];
    #pragma unroll
    for (int j = 0; j < 4; ++j) bfr[j] = *(const half8*)&Bs[(wn + j * 16 + lr) * 40 + lk];
    #pragma unroll
    for (int i = 0; i < 4; ++i)
      #pragma unroll
      for (int j = 0; j < 4; ++j)
        acc[i][j] = __builtin_amdgcn_mfma_f32_16x16x32_f16(af[i], bfr[j], acc[i][j], 0, 0, 0);
  }
  const int mb = m0 + wm + (lane >> 4) * 4;
  const int nb = n0 + wn + (lane & 15);
  #pragma unroll
  for (int i = 0; i < 4; ++i)
    #pragma unroll
    for (int j = 0; j < 4; ++j)
      #pragma unroll
      for (int r = 0; r < 4; ++r) {
        size_t idx = (size_t)(mb + i * 16 + r) * N + (nb + j * 16);
        float val = acc[i][j][r];
        if constexpr (EPI == 1) val += Res[idx];
        C[idx] = val;
      }
}

__global__ __launch_bounds__(256, 2) void gemm_gateup(
    const _Float16* __restrict__ A, const float* __restrict__ Wg,
    const float* __restrict__ Wu, _Float16* __restrict__ Act) {
  const int K = DM;
  const int m0 = blockIdx.x * 128;
  const int n0 = blockIdx.y * 128;
  __shared__ _Float16 As[128 * 40];
  __shared__ _Float16 Bgs[128 * 40];
  __shared__ _Float16 Bus[128 * 40];
  const int tid = threadIdx.x;
  const int lane = tid & 63;
  const int wave = tid >> 6;
  const int wm = (wave >> 1) * 64, wn = (wave & 1) * 64;
  const int lr = lane & 15, lk = (lane >> 4) * 8;
  const int r2 = tid >> 1, kh = (tid & 1) * 16;
  const _Float16* Ag = A + (size_t)(m0 + r2) * K + kh;
  const float* Bgg = Wg + (size_t)(n0 + r2) * K + kh;
  const float* Bgu = Wu + (size_t)(n0 + r2) * K + kh;
  _Float16* AsW = &As[r2 * 40 + kh];
  _Float16* BgW = &Bgs[r2 * 40 + kh];
  _Float16* BuW = &Bus[r2 * 40 + kh];
  floatx4 ag[4][4], au[4][4];
  #pragma unroll
  for (int i = 0; i < 4; ++i)
    #pragma unroll
    for (int j = 0; j < 4; ++j) {
      ag[i][j] = (floatx4){0.f, 0.f, 0.f, 0.f};
      au[i][j] = (floatx4){0.f, 0.f, 0.f, 0.f};
    }
  for (int kt = 0; kt < K; kt += 32) {
    float4 a0 = *(const float4*)(Ag);
    float4 a1 = *(const float4*)(Ag + 8);
    float4 g0 = *(const float4*)(Bgg);
    float4 g1 = *(const float4*)(Bgg + 4);
    float4 g2 = *(const float4*)(Bgg + 8);
    float4 g3 = *(const float4*)(Bgg + 12);
    float4 u0 = *(const float4*)(Bgu);
    float4 u1 = *(const float4*)(Bgu + 4);
    float4 u2 = *(const float4*)(Bgu + 8);
    float4 u3 = *(const float4*)(Bgu + 12);
    Ag += 32; Bgg += 32; Bgu += 32;
    half8 hg0, hg1, hu0, hu1;
    hg0[0]=(_Float16)g0.x; hg0[1]=(_Float16)g0.y; hg0[2]=(_Float16)g0.z; hg0[3]=(_Float16)g0.w;
    hg0[4]=(_Float16)g1.x; hg0[5]=(_Float16)g1.y; hg0[6]=(_Float16)g1.z; hg0[7]=(_Float16)g1.w;
    hg1[0]=(_Float16)g2.x; hg1[1]=(_Float16)g2.y; hg1[2]=(_Float16)g2.z; hg1[3]=(_Float16)g2.w;
    hg1[4]=(_Float16)g3.x; hg1[5]=(_Float16)g3.y; hg1[6]=(_Float16)g3.z; hg1[7]=(_Float16)g3.w;
    hu0[0]=(_Float16)u0.x; hu0[1]=(_Float16)u0.y; hu0[2]=(_Float16)u0.z; hu0[3]=(_Float16)u0.w;
    hu0[4]=(_Float16)u1.x; hu0[5]=(_Float16)u1.y; hu0[6]=(_Float16)u1.z; hu0[7]=(_Float16)u1.w;
    hu1[0]=(_Float16)u2.x; hu1[1]=(_Float16)u2.y; hu1[2]=(_Float16)u2.z; hu1[3]=(_Float16)u2.w;
    hu1[4]=(_Float16)u3.x; hu1[5]=(_Float16)u3.y; hu1[6]=(_Float16)u3.z; hu1[7]=(_Float16)u3.w;
    __syncthreads();
    *(float4*)AsW = a0;
    *(float4*)(AsW + 8) = a1;
    *(half8*)BgW = hg0; *(half8*)(BgW + 8) = hg1;
    *(half8*)BuW = hu0; *(half8*)(BuW + 8) = hu1;
    __syncthreads();
    half8 af[4], bg[4], bu[4];
    #pragma unroll
    for (int i = 0; i < 4; ++i) af[i] = *(const half8*)&As[(wm + i * 16 + lr) * 40 + lk];
    #pragma unroll
    for (int j = 0; j < 4; ++j) {
      bg[j] = *(const half8*)&Bgs[(wn + j * 16 + lr) * 40 + lk];
      bu[j] = *(const half8*)&Bus[(wn + j * 16 + lr) * 40 + lk];
    }
    #pragma unroll
    for (int i = 0; i < 4; ++i)
      #pragma unroll
      for (int j = 0; j < 4; ++j) {
        ag[i][j] = __builtin_amdgcn_mfma_f32_16x16x32_f16(af[i], bg[j], ag[i][j], 0, 0, 0);
        au[i][j] = __builtin_amdgcn_mfma_f32_16x16x32_f16(af[i], bu[j], au[i][j], 0, 0, 0);
      }
  }
  const int mb = m0 + wm + (lane >> 4) * 4;
  const int nb = n0 + wn + (lane & 15);
  #pragma unroll
  for (int i = 0; i < 4; ++i)
    #pragma unroll
    for (int j = 0; j < 4; ++j)
      #pragma unroll
      for (int r = 0; r < 4; ++r) {
        size_t idx = (size_t)(mb + i * 16 + r) * FF + (nb + j * 16);
        Act[idx] = (_Float16)(gelu_tanh(ag[i][j][r]) * au[i][j][r]);
      }
}

// ---------------- RoPE (repo transpose bug: angle uses pos_ids[s,b]) ----------------
__global__ __launch_bounds__(256) void rope_kernel(
    float* __restrict__ x, const int* __restrict__ pos_ids,
    const float* __restrict__ inv_freq, int nh, int ld, int total) {
  int tid = blockIdx.x * 256 + threadIdx.x;
  if (tid >= total) return;
  int i = tid & 127;
  int rest = tid >> 7;
  int hh = rest % nh;
  int m = rest / nh;                 // b*64 + s
  int b = m >> 6, s = m & 63;
  int pos = pos_ids[s * 64 + b];     // transposed indexing (B==S)
  float fr = inv_freq[i] * (float)pos;
  float c = cosf(fr), sn = sinf(fr);
  size_t base = (size_t)m * ld + (size_t)hh * 256 + i;
  float x1 = x[base], x2 = x[base + 128];
  x[base] = x1 * c - x2 * sn;
  x[base + 128] = x2 * c + x1 * sn;
}

// ---------------- attention (strided q/k/v) ----------------
__global__ __launch_bounds__(256) void attn_kernel(
    const float* __restrict__ qbase, int qld,
    const float* __restrict__ kbase, int kld,
    const float* __restrict__ vbase, int vld,
    const float* __restrict__ mask, float* __restrict__ attn_out, _Float16* __restrict__ ctx) {
  const int bh = blockIdx.x;
  const int b = bh >> 3, h = bh & 7;
  __shared__ __align__(16) char smem[65536];
  const int tid = threadIdx.x;
  for (int it = 0; it < 16; ++it) {
    int f = it * 256 + tid;
    int t = f >> 6, d4 = f & 63;
    float4 kv = *(const float4*)(kbase + (size_t)(b * 64 + t) * kld + d4 * 4);
    int col = d4 ^ ((t >> 2) & 7);
    *(float4*)(smem + t * 1024 + col * 16) = kv;
  }
  __syncthreads();
  const int sg = tid >> 4, tg = tid & 15;
  const int s0 = sg * 4, t0 = tg * 4;
  float sc[4][4] = {};
  const float* qb = qbase + (size_t)(b * 64 + s0) * qld + h * HDIM;
  for (int d4 = 0; d4 < 64; ++d4) {
    float4 kvv[4];
    int col = d4 ^ (tg & 7);
    #pragma unroll
    for (int j = 0; j < 4; ++j)
      kvv[j] = *(const float4*)(smem + (t0 + j) * 1024 + col * 16);
    #pragma unroll
    for (int i = 0; i < 4; ++i) {
      float4 qv = *(const float4*)(qb + (size_t)i * qld + d4 * 4);
      #pragma unroll
      for (int j = 0; j < 4; ++j)
        sc[i][j] += qv.x * kvv[j].x + qv.y * kvv[j].y + qv.z * kvv[j].z + qv.w * kvv[j].w;
    }
  }
  float a16[4][4];
  const float* mrow = mask + (size_t)b * SEQ * SEQ;
  #pragma unroll
  for (int i = 0; i < 4; ++i) {
    const float4 mk = *(const float4*)(mrow + (size_t)(s0 + i) * SEQ + t0);
    float xh[4];
    xh[0] = f16r(sc[i][0] * 0.0625f + mk.x);
    xh[1] = f16r(sc[i][1] * 0.0625f + mk.y);
    xh[2] = f16r(sc[i][2] * 0.0625f + mk.z);
    xh[3] = f16r(sc[i][3] * 0.0625f + mk.w);
    float mx = fmaxf(fmaxf(xh[0], xh[1]), fmaxf(xh[2], xh[3]));
    #pragma unroll
    for (int off = 1; off < 16; off <<= 1) mx = fmaxf(mx, __shfl_xor(mx, off, 64));
    float ssum = 0.f;
    #pragma unroll
    for (int j = 0; j < 4; ++j) {
      float e = f16r(expf(f16r(xh[j] - mx)));
      a16[i][j] = e;
      ssum += e;
    }
    #pragma unroll
    for (int off = 1; off < 16; off <<= 1) ssum += __shfl_xor(ssum, off, 64);
    #pragma unroll
    for (int j = 0; j < 4; ++j) a16[i][j] = f16r(a16[i][j] / ssum);
  }
  float* ab = attn_out + (size_t)bh * SEQ * SEQ;
  #pragma unroll
  for (int i = 0; i < 4; ++i) {
    float4 av = {a16[i][0], a16[i][1], a16[i][2], a16[i][3]};
    *(float4*)(ab + (size_t)(s0 + i) * SEQ + t0) = av;
  }
  __syncthreads();
  float* as = (float*)smem;
  _Float16* vs = (_Float16*)(smem + 64 * 65 * 4);
  #pragma unroll
  for (int i = 0; i < 4; ++i)
    #pragma unroll
    for (int j = 0; j < 4; ++j)
      as[(s0 + i) * 65 + t0 + j] = a16[i][j];
  for (int it = 0; it < 16; ++it) {
    int f = it * 256 + tid;
    int t = f >> 6, d4 = f & 63;
    float4 vv = *(const float4*)(vbase + (size_t)(b * 64 + t) * vld + d4 * 4);
    half4v hv;
    hv[0] = (_Float16)vv.x; hv[1] = (_Float16)vv.y;
    hv[2] = (_Float16)vv.z; hv[3] = (_Float16)vv.w;
    *(half4v*)(vs + t * 264 + d4 * 4) = hv;
  }
  __syncthreads();
  floatx4 outv[4][4];
  #pragma unroll
  for (int i = 0; i < 4; ++i)
    #pragma unroll
    for (int u = 0; u < 4; ++u) outv[i][u] = (floatx4){0.f, 0.f, 0.f, 0.f};
  for (int t = 0; t < 64; ++t) {
    float av[4];
    #pragma unroll
    for (int i = 0; i < 4; ++i) av[i] = as[(s0 + i) * 65 + t];
    #pragma unroll
    for (int u = 0; u < 4; ++u) {
      half4v vh = *(const half4v*)(vs + t * 264 + tg * 4 + u * 64);
      floatx4 vf = {(float)vh[0], (float)vh[1], (float)vh[2], (float)vh[3]};
      #pragma unroll
      for (int i = 0; i < 4; ++i) outv[i][u] += vf * av[i];
    }
  }
  #pragma unroll
  for (int i = 0; i < 4; ++i)
    #pragma unroll
    for (int u = 0; u < 4; ++u) {
      half4v hv;
      hv[0] = (_Float16)outv[i][u][0];
      hv[1] = (_Float16)outv[i][u][1];
      hv[2] = (_Float16)outv[i][u][2];
      hv[3] = (_Float16)outv[i][u][3];
      *(half4v*)(ctx + (size_t)(b * 64 + s0 + i) * DM + h * HDIM + u * 64 + tg * 4) = hv;
    }
}

extern "C" void kernel_launch(void* const* d_in, const int* in_sizes, int n_in,
                              void* d_out, int out_size, void* d_ws, size_t ws_size,
                              hipStream_t stream) {
  const float* hs   = (const float*)d_in[0];
  const float* mask = (const float*)d_in[1];
  const int*   pos  = (const int*)d_in[2];
  const float* invf = (const float*)d_in[3];
  const float* wq   = (const float*)d_in[4];
  const float* wk   = (const float*)d_in[5];
  const float* wv   = (const float*)d_in[6];
  const float* wo   = (const float*)d_in[7];
  const float* wg   = (const float*)d_in[8];
  const float* wu   = (const float*)d_in[9];
  const float* wd   = (const float*)d_in[10];
  const float* ln1  = (const float*)d_in[11];
  const float* ln2  = (const float*)d_in[12];

  float* out_hidden = (float*)d_out;                 // (64,64,2048) f32
  float* out_attn   = out_hidden + 8388608;          // (64,8,64,64) f32

  const size_t FULL_NEED = 352321536;                // 336 MiB
  char* ws = (char*)d_ws;

  if (ws_size >= FULL_NEED) {
    // ---- full path: f16 weights + global_load_lds GEMMs ----
    _Float16* h_half = (_Float16*)(ws);                        // 16.8 MB
    _Float16* wg_h   = (_Float16*)(ws + 16777216);             // 67.1 MB
    _Float16* wu_h   = (_Float16*)(ws + 83886080);             // 67.1 MB
    _Float16* wd_h   = (_Float16*)(ws + 150994944);            // 67.1 MB
    char*     rx     = ws + 218103808;                         // union region (134.2 MB)
    _Float16* qkvw   = (_Float16*)(rx);                        // [2560][2048] f16
    _Float16* wo_h   = (_Float16*)(rx + 10485760);
    float*    qkv    = (float*)(rx + 18874368);                // [4096][2560] f32
    _Float16* ctx    = (_Float16*)(rx + 60817408);             // [4096][2048] f16
    _Float16* act    = (_Float16*)(rx);                        // [4096][16384] f16 (after attn/o-proj)

    convert_f16<<<2048, 256, 0, stream>>>(wq, qkvw, 524288);
    convert_f16<<<256,  256, 0, stream>>>(wk, qkvw + (size_t)2048 * 2048, 65536);
    convert_f16<<<256,  256, 0, stream>>>(wv, qkvw + (size_t)2304 * 2048, 65536);
    convert_f16<<<2048, 256, 0, stream>>>(wo, wo_h, 524288);
    convert_f16<<<16384, 256, 0, stream>>>(wg, wg_h, 4194304);
    convert_f16<<<16384, 256, 0, stream>>>(wu, wu_h, 4194304);
    convert_f16<<<16384, 256, 0, stream>>>(wd, wd_h, 4194304);

    rmsnorm_kernel<<<4096, 256, 0, stream>>>(hs, ln1, h_half);
    gemm_lds<0><<<dim3(32, 20), 256, 0, stream>>>(h_half, qkvw, qkv, nullptr, 2560, 2048);
    rope_kernel<<<18432, 256, 0, stream>>>(qkv, pos, invf, 9, 2560, 4096 * 9 * 128);
    attn_kernel<<<512, 256, 0, stream>>>(qkv, 2560, qkv + 2048, 2560, qkv + 2304, 2560,
                                         mask, out_attn, ctx);
    gemm_lds<1><<<dim3(32, 16), 256, 0, stream>>>(ctx, wo_h, out_hidden, hs, 2048, 2048);
    rmsnorm_kernel<<<4096, 256, 0, stream>>>(out_hidden, ln2, h_half);
    gateup_lds<<<dim3(32, 256), 256, 0, stream>>>(h_half, wg_h, wu_h, act);
    gemm_lds<1><<<dim3(32, 16), 256, 0, stream>>>(act, wd_h, out_hidden, out_hidden, 2048, 16384);
  } else {
    // ---- fallback: R1 structure (151 MB) ----
    _Float16* h_half = (_Float16*)ws;
    char* Creg = ws + (size_t)16777216;
    float*     qb  = (float*)(Creg);
    float*     kb  = (float*)(Creg + 33554432);
    float*     vb  = (float*)(Creg + 37748736);
    _Float16*  ctx = (_Float16*)(Creg + 41943040);
    _Float16*  act = (_Float16*)(Creg);

    rmsnorm_kernel<<<4096, 256, 0, stream>>>(hs, ln1, h_half);
    gemm_f16<0><<<dim3(32, 16), 256, 0, stream>>>(h_half, wq, qb, nullptr, 2048, 2048);
    gemm_f16<0><<<dim3(32, 2),  256, 0, stream>>>(h_half, wk, kb, nullptr, 256, 2048);
    gemm_f16<0><<<dim3(32, 2),  256, 0, stream>>>(h_half, wv, vb, nullptr, 256, 2048);
    rope_kernel<<<16384, 256, 0, stream>>>(qb, pos, invf, 8, 2048, 4096 * 8 * 128);
    rope_kernel<<<2048,  256, 0, stream>>>(kb, pos, invf, 1, 256, 4096 * 1 * 128);
    attn_kernel<<<512, 256, 0, stream>>>(qb, 2048, kb, 256, vb, 256, mask, out_attn, ctx);
    gemm_f16<1><<<dim3(32, 16), 256, 0, stream>>>(ctx, wo, out_hidden, hs, 2048, 2048);
    rmsnorm_kernel<<<4096, 256, 0, stream>>>(out_hidden, ln2, h_half);
    gemm_gateup<<<dim3(32, 128), 256, 0, stream>>>(h_half, wg, wu, act);
    gemm_f16<1><<<dim3(32, 16), 256, 0, stream>>>(act, wd, out_hidden, out_hidden, 2048, 16384);
  }
}